// Round 6
// baseline (8012.525 us; speedup 1.0000x reference)
//
#include <hip/hip_runtime.h>
#include <hip/hip_bf16.h>

// ---------------------------------------------------------------------------
// fp32 probe GEMM: C[M=4096][N=2048] = A[M][K=2048] * W[N][K]^T.
// 64x64 tile, 256 threads as 16x16, 4x4 outputs each. All fp32.
// scatter=1: C[m=(b,s)][n=(h,d)] -> Out[b][h][s][d] (qkv layout).
// scatter=0: row-major C[m][n].
// ---------------------------------------------------------------------------
__global__ __launch_bounds__(256)
void gemm_f32(const float* __restrict__ A, const float* __restrict__ W,
              float* __restrict__ Out, int scatter)
{
    constexpr int K = 2048;
    const int bm = blockIdx.y * 64;
    const int bn = blockIdx.x * 64;
    const int tid = threadIdx.x;
    const int tx = tid & 15, ty = tid >> 4;

    __shared__ float As[64][65];
    __shared__ float Ws[64][65];

    float acc[4][4] = {{0.f}};

    for (int k0 = 0; k0 < K; k0 += 64) {
#pragma unroll
        for (int p = 0; p < 16; ++p) {
            const int idx = p * 256 + tid;
            const int r = idx >> 6, c = idx & 63;
            As[r][c] = A[(size_t)(bm + r) * K + k0 + c];
            Ws[r][c] = W[(size_t)(bn + r) * K + k0 + c];
        }
        __syncthreads();
#pragma unroll 4
        for (int kk = 0; kk < 64; ++kk) {
            float av[4], wv[4];
#pragma unroll
            for (int i = 0; i < 4; ++i) av[i] = As[ty * 4 + i][kk];
#pragma unroll
            for (int j = 0; j < 4; ++j) wv[j] = Ws[tx * 4 + j][kk];
#pragma unroll
            for (int i = 0; i < 4; ++i)
#pragma unroll
                for (int j = 0; j < 4; ++j) acc[i][j] += av[i] * wv[j];
        }
        __syncthreads();
    }

#pragma unroll
    for (int i = 0; i < 4; ++i) {
#pragma unroll
        for (int j = 0; j < 4; ++j) {
            const int row = bm + ty * 4 + i;
            const int col = bn + tx * 4 + j;
            const float v = acc[i][j];
            if (scatter) {
                const int b = row >> 11, s = row & 2047;
                const int h = col >> 7,  d = col & 127;
                Out[(((size_t)b * 16 + h) * 2048 + s) * 128 + d] = v;
            } else {
                Out[(size_t)row * 2048 + col] = v;   // fp32 final store
            }
        }
    }
}

// ---------------------------------------------------------------------------
// RoPE, fp32 in-place on [B][NH][S][HD]; folds 1/sqrt(128) into Q.
// q'[fi]    = q[fi]*cos(s*f) - q[fi+64]*sin(s*f)
// q'[fi+64] = q[fi+64]*cos(s*f) + q[fi]*sin(s*f),  f = 10000^(-fi/64)
// ---------------------------------------------------------------------------
__global__ __launch_bounds__(256)
void rope_f32(float* __restrict__ Q, float* __restrict__ Kb)
{
    const int idx = blockIdx.x * 256 + threadIdx.x;  // 2*16*2048*64 threads
    const int fi = idx & 63;
    const int s  = (idx >> 6) & 2047;
    const int bh = idx >> 17;
    const size_t base = ((size_t)bh * 2048 + s) * 128;

    const float inv = powf(10000.f, -(float)fi / 64.f);
    const float ang = (float)s * inv;
    const float c = cosf(ang), sn = sinf(ang);
    const float sc = 0.08838834764831845f;  // 1/sqrt(128)

    const float qlo = Q[base + fi], qhi = Q[base + fi + 64];
    Q[base + fi]      = (qlo * c - qhi * sn) * sc;
    Q[base + fi + 64] = (qhi * c + qlo * sn) * sc;

    const float klo = Kb[base + fi], khi = Kb[base + fi + 64];
    Kb[base + fi]      = klo * c - khi * sn;
    Kb[base + fi + 64] = khi * c + klo * sn;
}

// ---------------------------------------------------------------------------
// fp32 naive causal attention. Q pre-scaled. One block per (q-row, b*h).
// Q,K,V: [B][NH][S][HD] fp32; O: [B][S][NH][HD] fp32.
// ---------------------------------------------------------------------------
__global__ __launch_bounds__(256)
void attn_f32(const float* __restrict__ Qg, const float* __restrict__ Kg,
              const float* __restrict__ Vg, float* __restrict__ Og)
{
    const int qi = blockIdx.x;
    const int bh = blockIdx.y;
    const int b = bh >> 4, h = bh & 15;
    const size_t base = (size_t)bh * 2048 * 128;
    const int tid = threadIdx.x;
    const int n = qi + 1;

    __shared__ float Qs[128];
    __shared__ float sc[2048];
    __shared__ float red[256];

    if (tid < 128) Qs[tid] = Qg[base + (size_t)qi * 128 + tid];
    __syncthreads();

    float lmax = -1e30f;
    for (int j = tid; j < n; j += 256) {
        const float* kr = Kg + base + (size_t)j * 128;
        float s = 0.f;
#pragma unroll 8
        for (int c = 0; c < 128; ++c) s += Qs[c] * kr[c];
        sc[j] = s;
        lmax = fmaxf(lmax, s);
    }
    red[tid] = lmax;
    __syncthreads();
    for (int st = 128; st > 0; st >>= 1) {
        if (tid < st) red[tid] = fmaxf(red[tid], red[tid + st]);
        __syncthreads();
    }
    const float m = red[0];
    __syncthreads();

    float lsum = 0.f;
    for (int j = tid; j < n; j += 256) {
        const float p = __expf(sc[j] - m);
        sc[j] = p;
        lsum += p;
    }
    red[tid] = lsum;
    __syncthreads();
    for (int st = 128; st > 0; st >>= 1) {
        if (tid < st) red[tid] += red[tid + st];
        __syncthreads();
    }
    const float inv = 1.f / red[0];
    __syncthreads();

    if (tid < 128) {
        float acc = 0.f;
        for (int j = 0; j < n; ++j)
            acc += sc[j] * Vg[base + (size_t)j * 128 + tid];
        Og[(((size_t)b * 2048 + qi) * 16 + h) * 128 + tid] = acc * inv;
    }
}

// ---------------------------------------------------------------------------
extern "C" void kernel_launch(void* const* d_in, const int* in_sizes, int n_in,
                              void* d_out, int out_size, void* d_ws, size_t ws_size,
                              hipStream_t stream)
{
    // fp32 inputs, setup_inputs() dict order (sizes verified by r5 sentinels)
    const float* X  = (const float*)d_in[0];   // hidden_states [2][2048][2048]
    const float* Wq = (const float*)d_in[1];   // q_w [2048][2048]
    const float* Wk = (const float*)d_in[2];   // k_w
    const float* Wv = (const float*)d_in[3];   // v_w
    const float* Wo = (const float*)d_in[4];   // o_w
    // d_in[5] = attention_mask (causal, recomputed), d_in[6] = position_ids

    float* out = (float*)d_out;  // fp32 per contract: reference output dtype is float32

    float* q  = (float*)d_ws;        // [B][NH][S][HD] fp32, 8388608 elems each
    float* k  = q  + 8388608;
    float* v  = k  + 8388608;
    float* ao = v  + 8388608;        // [B][S][NH][HD] fp32  (total 128 MB)

    dim3 blk(256);
    gemm_f32<<<dim3(32, 64), blk, 0, stream>>>(X, Wq, q, 1);
    gemm_f32<<<dim3(32, 64), blk, 0, stream>>>(X, Wk, k, 1);
    gemm_f32<<<dim3(32, 64), blk, 0, stream>>>(X, Wv, v, 1);
    rope_f32<<<dim3(16384), blk, 0, stream>>>(q, k);
    attn_f32<<<dim3(2048, 32), blk, 0, stream>>>(q, k, v, ao);
    gemm_f32<<<dim3(32, 64), blk, 0, stream>>>(ao, Wo, out, 0);
}

// Round 7
// 557.903 us; speedup vs baseline: 14.3619x; 14.3619x over previous
//
#include <hip/hip_runtime.h>
#include <hip/hip_bf16.h>

using bf16 = __hip_bfloat16;
typedef short  short8  __attribute__((ext_vector_type(8)));
typedef float  float4_ __attribute__((ext_vector_type(4)));
typedef int    int4_   __attribute__((ext_vector_type(4)));

typedef __attribute__((address_space(1))) const void* gas_ptr;
typedef __attribute__((address_space(3))) void*       las_ptr;

#define MFMA_BF16(a, b, c) __builtin_amdgcn_mfma_f32_16x16x32_bf16((a), (b), (c), 0, 0, 0)

__device__ __forceinline__ float bf2f(bf16 v) { return __bfloat162float(v); }
__device__ __forceinline__ bf16  f2bf(float v) { return __float2bfloat16(v); }

// ---------------------------------------------------------------------------
// fp32 -> bf16 conversion of X + 4 weights into workspace (verified r2 form).
// ---------------------------------------------------------------------------
__global__ __launch_bounds__(256)
void cvt_all(const float* __restrict__ X,  const float* __restrict__ Wq,
             const float* __restrict__ Wk, const float* __restrict__ Wv,
             const float* __restrict__ Wo,
             bf16* __restrict__ Xb,  bf16* __restrict__ Wqb,
             bf16* __restrict__ Wkb, bf16* __restrict__ Wvb,
             bf16* __restrict__ Wob)
{
    const size_t i = ((size_t)blockIdx.x * 256 + threadIdx.x) * 8;
    const float* src; bf16* dst; size_t off;
    if (i < 8388608)       { src = X;  dst = Xb;  off = i; }
    else if (i < 12582912) { src = Wq; dst = Wqb; off = i - 8388608; }
    else if (i < 16777216) { src = Wk; dst = Wkb; off = i - 12582912; }
    else if (i < 20971520) { src = Wv; dst = Wvb; off = i - 16777216; }
    else                   { src = Wo; dst = Wob; off = i - 20971520; }
    const float4_ a = *(const float4_*)(src + off);
    const float4_ b = *(const float4_*)(src + off + 4);
    union { short8 s; bf16 h[8]; } u;
#pragma unroll
    for (int j = 0; j < 4; ++j) { u.h[j] = f2bf(a[j]); u.h[j + 4] = f2bf(b[j]); }
    *(short8*)(dst + off) = u.s;
}

// ---------------------------------------------------------------------------
// MFMA GEMM (function-verified r2-4): C[4096][2048] = A * W^T, bf16, fp32 acc.
// m97 structure: 128x128 tile, 4 waves 2x2, global_load_lds w=16, BK=32.
// mode 0: scatter bf16 to Out[b][h][s][d] (qkv). mode 1: row-major fp32 OutF.
// ---------------------------------------------------------------------------
__global__ __launch_bounds__(256)
void gemm128(const bf16* __restrict__ A,
             const bf16* __restrict__ W0, const bf16* __restrict__ W1, const bf16* __restrict__ W2,
             bf16* __restrict__ O0, bf16* __restrict__ O1, bf16* __restrict__ O2,
             float* __restrict__ OF, int mode)
{
    constexpr int K = 2048;
    const int z = blockIdx.z;
    const bf16* W  = (z == 0) ? W0 : (z == 1) ? W1 : W2;
    bf16*      Out = (z == 0) ? O0 : (z == 1) ? O1 : O2;

    const int bm = blockIdx.y * 128;
    const int bn = blockIdx.x * 128;

    const int tid  = threadIdx.x;
    const int wave = tid >> 6;
    const int ln   = tid & 63;
    const int r15  = ln & 15;
    const int quad = ln >> 4;
    const int wr   = wave >> 1, wc = wave & 1;

    __shared__ bf16 As[128 * 32];
    __shared__ bf16 Bs[128 * 32];

    float4_ acc[4][4];
    const float4_ fzero = {0.f, 0.f, 0.f, 0.f};
#pragma unroll
    for (int i = 0; i < 4; ++i)
#pragma unroll
        for (int j = 0; j < 4; ++j) acc[i][j] = fzero;

    const int srow = ln >> 2;
    const int scg  = (ln & 3) * 8;

    for (int kt = 0; kt < K / 32; ++kt) {
        const int k0 = kt * 32;
#pragma unroll
        for (int c = 0; c < 2; ++c) {
            const int rb = (wave * 2 + c) * 16;
            const bf16* ga = A + (size_t)(bm + rb + srow) * K + k0 + scg;
            const bf16* gb = W + (size_t)(bn + rb + srow) * K + k0 + scg;
            __builtin_amdgcn_global_load_lds((gas_ptr)ga, (las_ptr)(&As[rb * 32]), 16, 0, 0);
            __builtin_amdgcn_global_load_lds((gas_ptr)gb, (las_ptr)(&Bs[rb * 32]), 16, 0, 0);
        }
        __syncthreads();

        short8 af[4], bfr[4];
#pragma unroll
        for (int i = 0; i < 4; ++i)
            af[i] = *(const short8*)&As[(wr * 64 + i * 16 + r15) * 32 + quad * 8];
#pragma unroll
        for (int j = 0; j < 4; ++j)
            bfr[j] = *(const short8*)&Bs[(wc * 64 + j * 16 + r15) * 32 + quad * 8];
#pragma unroll
        for (int i = 0; i < 4; ++i)
#pragma unroll
            for (int j = 0; j < 4; ++j)
                acc[i][j] = MFMA_BF16(af[i], bfr[j], acc[i][j]);
        __syncthreads();
    }

#pragma unroll
    for (int i = 0; i < 4; ++i) {
#pragma unroll
        for (int j = 0; j < 4; ++j) {
#pragma unroll
            for (int r = 0; r < 4; ++r) {
                const int row = bm + wr * 64 + i * 16 + quad * 4 + r;
                const int col = bn + wc * 64 + j * 16 + r15;
                const float v = acc[i][j][r];
                if (mode == 0) {
                    const int b = row >> 11, s = row & 2047;
                    const int h = col >> 7,  d = col & 127;
                    Out[(((size_t)b * 16 + h) * 2048 + s) * 128 + d] = f2bf(v);
                } else {
                    OF[(size_t)row * 2048 + col] = v;   // fp32 final output
                }
            }
        }
    }
}

// ---------------------------------------------------------------------------
// RoPE on Q and K ([B][NH][S][HD] bf16); folds 1/sqrt(128) into Q.
// ---------------------------------------------------------------------------
__global__ __launch_bounds__(256)
void rope_scale(bf16* __restrict__ Q, bf16* __restrict__ Kb)
{
    const int idx = blockIdx.x * 256 + threadIdx.x;
    const int d  = idx & 63;
    const int s  = (idx >> 6) & 2047;
    const int bh = idx >> 17;
    const size_t base = ((size_t)bh * 2048 + s) * 128;

    const float inv_freq = expf(-(float)d * (9.210340371976184f / 64.f));
    const float ang = (float)s * inv_freq;
    const float c = cosf(ang), sn = sinf(ang);
    const float sc = 0.08838834764831845f;

    const float q1 = bf2f(Q[base + d]), q2 = bf2f(Q[base + d + 64]);
    Q[base + d]      = f2bf((q1 * c - q2 * sn) * sc);
    Q[base + d + 64] = f2bf((q2 * c + q1 * sn) * sc);

    const float k1 = bf2f(Kb[base + d]), k2 = bf2f(Kb[base + d + 64]);
    Kb[base + d]      = f2bf(k1 * c - k2 * sn);
    Kb[base + d + 64] = f2bf(k2 * c + k1 * sn);
}

// ---------------------------------------------------------------------------
// Causal MFMA flash attention (function-verified r2 vs naive). Q pre-scaled.
// Q,K,V: [B][NH][S][HD] bf16; O: [B][S][NH][HD] bf16.
// ---------------------------------------------------------------------------
__global__ __launch_bounds__(256)
void flash_attn(const bf16* __restrict__ Qg, const bf16* __restrict__ Kg,
                const bf16* __restrict__ Vg, bf16* __restrict__ Og)
{
    constexpr int S = 2048;
    const int qb = blockIdx.x;
    const int bh = blockIdx.y;
    const int b = bh >> 4, h = bh & 15;
    const size_t base = (size_t)bh * S * 128;
    const bf16* Qp = Qg + base;
    const bf16* Kp = Kg + base;
    const bf16* Vp = Vg + base;

    const int tid  = threadIdx.x;
    const int wave = tid >> 6;
    const int ln   = tid & 63;
    const int r15  = ln & 15;
    const int quad = ln >> 4;

    __shared__ bf16 Qs[64][136];
    __shared__ bf16 Ks[64][136];
    __shared__ bf16 Vt[128][72];
    __shared__ bf16 Ps[4][16][72];

    const int qs = qb * 64;

    {
        const int r = tid >> 4;
        const int c = (tid & 15) * 8;
#pragma unroll
        for (int p = 0; p < 4; ++p)
            *(int4_*)&Qs[r + p * 16][c] =
                *(const int4_*)&Qp[(size_t)(qs + r + p * 16) * 128 + c];
    }
    __syncthreads();

    short8 qf[4];
#pragma unroll
    for (int ks = 0; ks < 4; ++ks)
        qf[ks] = *(const short8*)&Qs[wave * 16 + r15][ks * 32 + quad * 8];

    float4_ acc_o[8];
    const float4_ fzero = {0.f, 0.f, 0.f, 0.f};
#pragma unroll
    for (int of = 0; of < 8; ++of) acc_o[of] = fzero;
    float m_run[4], l_run[4];
#pragma unroll
    for (int r = 0; r < 4; ++r) { m_run[r] = -__builtin_inff(); l_run[r] = 0.f; }

    for (int kt = 0; kt <= qb; ++kt) {
        __syncthreads();
        {
            const int r = tid >> 4;
            const int c = (tid & 15) * 8;
#pragma unroll
            for (int p = 0; p < 4; ++p)
                *(int4_*)&Ks[r + p * 16][c] =
                    *(const int4_*)&Kp[(size_t)(kt * 64 + r + p * 16) * 128 + c];
        }
        {
#pragma unroll
            for (int p = 0; p < 4; ++p) {
                const int d0 = wave * 8 + p * 32;
                alignas(16) bf16 tmp[8];
                *(int4_*)tmp = *(const int4_*)&Vp[(size_t)(kt * 64 + ln) * 128 + d0];
#pragma unroll
                for (int j = 0; j < 8; ++j)
                    Vt[d0 + j][ln] = tmp[j];
            }
        }
        __syncthreads();

        float4_ sacc[4];
#pragma unroll
        for (int nf = 0; nf < 4; ++nf) {
            sacc[nf] = fzero;
#pragma unroll
            for (int ks = 0; ks < 4; ++ks) {
                short8 kf = *(const short8*)&Ks[nf * 16 + r15][ks * 32 + quad * 8];
                sacc[nf] = MFMA_BF16(qf[ks], kf, sacc[nf]);
            }
        }

        if (kt == qb) {
#pragma unroll
            for (int nf = 0; nf < 4; ++nf) {
                const int col = nf * 16 + r15;
#pragma unroll
                for (int r = 0; r < 4; ++r) {
                    const int row = wave * 16 + quad * 4 + r;
                    if (col > row) sacc[nf][r] = -__builtin_inff();
                }
            }
        }

        float mnew[4], alpha[4];
#pragma unroll
        for (int r = 0; r < 4; ++r) {
            float rm = fmaxf(fmaxf(sacc[0][r], sacc[1][r]),
                             fmaxf(sacc[2][r], sacc[3][r]));
            rm = fmaxf(rm, __shfl_xor(rm, 1));
            rm = fmaxf(rm, __shfl_xor(rm, 2));
            rm = fmaxf(rm, __shfl_xor(rm, 4));
            rm = fmaxf(rm, __shfl_xor(rm, 8));
            mnew[r]  = fmaxf(m_run[r], rm);
            alpha[r] = __expf(m_run[r] - mnew[r]);
            m_run[r] = mnew[r];
        }
        float rs[4] = {0.f, 0.f, 0.f, 0.f};
#pragma unroll
        for (int nf = 0; nf < 4; ++nf) {
#pragma unroll
            for (int r = 0; r < 4; ++r) {
                const float p = __expf(sacc[nf][r] - mnew[r]);
                rs[r] += p;
                Ps[wave][quad * 4 + r][nf * 16 + r15] = f2bf(p);
            }
        }
#pragma unroll
        for (int r = 0; r < 4; ++r) {
            float t = rs[r];
            t += __shfl_xor(t, 1);
            t += __shfl_xor(t, 2);
            t += __shfl_xor(t, 4);
            t += __shfl_xor(t, 8);
            l_run[r] = l_run[r] * alpha[r] + t;
        }
#pragma unroll
        for (int of = 0; of < 8; ++of)
#pragma unroll
            for (int r = 0; r < 4; ++r)
                acc_o[of][r] *= alpha[r];

#pragma unroll
        for (int k2 = 0; k2 < 2; ++k2) {
            short8 pf = *(const short8*)&Ps[wave][r15][k2 * 32 + quad * 8];
#pragma unroll
            for (int of = 0; of < 8; ++of) {
                short8 vf = *(const short8*)&Vt[of * 16 + r15][k2 * 32 + quad * 8];
                acc_o[of] = MFMA_BF16(pf, vf, acc_o[of]);
            }
        }
    }

#pragma unroll
    for (int r = 0; r < 4; ++r) {
        const float inv = 1.f / l_run[r];
        const int  s  = qs + wave * 16 + quad * 4 + r;
        const size_t ob = (((size_t)b * S + s) * 16 + h) * 128;
#pragma unroll
        for (int of = 0; of < 8; ++of)
            Og[ob + of * 16 + r15] = f2bf(acc_o[of][r] * inv);
    }
}

// ---------------------------------------------------------------------------
extern "C" void kernel_launch(void* const* d_in, const int* in_sizes, int n_in,
                              void* d_out, int out_size, void* d_ws, size_t ws_size,
                              hipStream_t stream)
{
    // fp32 inputs in setup_inputs() dict order (verified r5/r6)
    const float* X  = (const float*)d_in[0];
    const float* Wq = (const float*)d_in[1];
    const float* Wk = (const float*)d_in[2];
    const float* Wv = (const float*)d_in[3];
    const float* Wo = (const float*)d_in[4];
    float* out = (float*)d_out;              // fp32 output (verified r6)

    // ws (bf16 elems): 112 MB total, ws >= 128 MB verified
    bf16* Xb  = (bf16*)d_ws;                 // 8388608
    bf16* Wqb = Xb  + 8388608;               // 4194304 each
    bf16* Wkb = Wqb + 4194304;
    bf16* Wvb = Wkb + 4194304;
    bf16* Wob = Wvb + 4194304;
    bf16* q   = Wob + 4194304;               // [B][NH][S][HD] 8388608 each
    bf16* k   = q   + 8388608;
    bf16* v   = k   + 8388608;
    bf16* ao  = v   + 8388608;               // [B][S][NH][HD]

    dim3 blk(256);
    cvt_all<<<dim3(12288), blk, 0, stream>>>(X, Wq, Wk, Wv, Wo,
                                             Xb, Wqb, Wkb, Wvb, Wob);
    gemm128<<<dim3(16, 32, 3), blk, 0, stream>>>(Xb, Wqb, Wkb, Wvb,
                                                 q, k, v, nullptr, 0);
    rope_scale<<<dim3((2 * 16 * 2048 * 64) / 256), blk, 0, stream>>>(q, k);
    flash_attn<<<dim3(32, 32), blk, 0, stream>>>(q, k, v, ao);
    gemm128<<<dim3(16, 32, 1), blk, 0, stream>>>(ao, Wob, Wob, Wob,
                                                 nullptr, nullptr, nullptr, out, 1);
}